// Round 2
// baseline (2428.753 us; speedup 1.0000x reference)
//
#include <hip/hip_runtime.h>
#include <hip/hip_bf16.h>
#include <math.h>

#ifndef M_PI
#define M_PI 3.14159265358979323846
#endif

// fast f32 hardware transcendentals, with compile-safe fallbacks
#if __has_builtin(__builtin_amdgcn_exp2f)
#define EXP2F(x) __builtin_amdgcn_exp2f(x)
#else
#define EXP2F(x) __expf((x) * 0.6931471805599453f)
#endif
#if __has_builtin(__builtin_amdgcn_sqrtf)
#define SQRTF(x) __builtin_amdgcn_sqrtf(x)
#else
#define SQRTF(x) sqrtf(x)
#endif
#if __has_builtin(__builtin_amdgcn_rcpf)
#define RCPF(x) __builtin_amdgcn_rcpf(x)
#else
#define RCPF(x) (1.0f / (x))
#endif

template <int CTRL, int RM, int BM, bool BC>
__device__ __forceinline__ float dpp0f(float v) {
  // masked-out / invalid-source lanes contribute 0 (old = 0)
  return __int_as_float(
      __builtin_amdgcn_update_dpp(0, __float_as_int(v), CTRL, RM, BM, BC));
}

__device__ __forceinline__ float bcast_lane(float v, int lane) {
  return __int_as_float(__builtin_amdgcn_readlane(__float_as_int(v), lane));
}

// One serial step of the recurrence. All lanes execute redundantly on the
// uniform (k, vv); lanes 0..31 carry the 32 positive GL nodes (x-symmetry of
// sech^2 folds the negative nodes, weight doubled), lanes 32..63 have C=0.
__device__ __forceinline__ void one_step(float ut, float C, float m,
                                         float& k, float& vv) {
  const float u2 = ut * ut;
  const float d2 = fmaf(k, k, u2);       // delta^2 = k^2 + u^2
  const float dl = SQRTF(d2);            // delta
  const float w  = EXP2F(dl * m);        // w = exp(-2*delta*|X_q|) <= 1
  const float den = 1.0f + w;
  const float rr  = RCPF(den * den);
  float g = C * (w * rr);                // c_q * sech^2(delta * X_q)
  // wave-sum of lanes 0..31 into lane 31 (5 DPP adds)
  g += dpp0f<0x111, 0xF, 0xF, true >(g); // row_shr:1
  g += dpp0f<0x112, 0xF, 0xF, true >(g); // row_shr:2
  g += dpp0f<0x114, 0xF, 0xF, true >(g); // row_shr:4
  g += dpp0f<0x118, 0xF, 0xF, true >(g); // row_shr:8  -> lane15/31 hold row sums
  g += dpp0f<0x142, 0xA, 0xF, false>(g); // row_bcast:15 into row 1 -> lane 31 total
  const float G = bcast_lane(g, 31);     // gauss_int (already / 2pi)
  // k += 0.2*(-k + 1.4*G*k + 2.6*G*v)  ==  k*(0.8+0.28G) + 0.52*G*v
  const float coef = fmaf(0.28f, G, 0.8f);
  const float gv   = (0.52f * G) * vv;
  k  = fmaf(k, coef, gv);
  vv = fmaf(0.2f, ut - vv, vv);          // v += 0.2*(u - v)
}

__global__ __launch_bounds__(64)
void odim_scan(const float* __restrict__ u, float* __restrict__ out, int n) {
  const int lane = threadIdx.x;

  // ---- one-time: 64-pt Gauss-Legendre nodes/weights via Newton on P_64 ----
  // lane i owns root i (i<32 are the positive roots). f64 => matches
  // np.polynomial.legendre.leggauss to f32 ulp.
  double x = cos(M_PI * ((double)lane + 0.75) / 64.5);
  double dp = 1.0;
  for (int it = 0; it < 6; ++it) {
    double p0 = 1.0, p1 = x;
    for (int j = 2; j <= 64; ++j) {
      double p2 =
          ((2.0 * (double)j - 1.0) * x * p1 - ((double)j - 1.0) * p0) /
          (double)j;
      p0 = p1;
      p1 = p2;
    }
    dp = 64.0 * (x * p1 - p0) / (x * x - 1.0);   // P'_64(x)
    x -= p1 / dp;                                 // Newton
  }
  const double wq = 2.0 / ((1.0 - x * x) * dp * dp);

  const float Xf = (float)(x * 5.0);   // node scaled to [-5,5]  (A = 5)
  const float Wf = (float)(wq * 5.0);  // weight scaled by A
  const float ew = Wf * expf(-0.5f * Xf * Xf);  // fold exp(-z^2/2)
  // fold 1/(2pi) (ref), *4 (sech2 formula), *2 (+-node symmetry)
  const float C = (lane < 32) ? (ew * 0.15915494309189535f * 8.0f) : 0.0f;
  const float m = -2.8853900817779268f * fabsf(Xf);  // -2*log2(e)*|X_q|

  // ---- serial scan ----
  float k = 0.0f, vv = 0.0f;
  const int nch = n >> 6;
  float uu = (lane < n) ? u[lane] : 0.0f;  // chunk 0
  for (int c = 0; c < nch; ++c) {
    const int nb = (c + 1) << 6;
    float uun = 0.0f;
    if (nb + lane < n) uun = u[nb + lane];  // prefetch next chunk
#pragma unroll
    for (int j = 0; j < 64; ++j) {
      one_step(bcast_lane(uu, j), C, m, k, vv);
    }
    uu = uun;
  }
  // tail (n % 64) — not hit for n = 32768, kept for robustness
  const int rem = n - (nch << 6);
  for (int j = 0; j < rem; ++j) {
    one_step(bcast_lane(uu, j), C, m, k, vv);
  }

  if (lane == 0) out[0] = tanhf(k);  // reference output dtype is float32
}

extern "C" void kernel_launch(void* const* d_in, const int* in_sizes, int n_in,
                              void* d_out, int out_size, void* d_ws,
                              size_t ws_size, hipStream_t stream) {
  (void)n_in;
  (void)out_size;
  (void)d_ws;
  (void)ws_size;
  const float* u = (const float*)d_in[0];
  float* out = (float*)d_out;
  const int n = in_sizes[0];
  odim_scan<<<dim3(1), dim3(64), 0, stream>>>(u, out, n);
}